// Round 7
// baseline (2777.362 us; speedup 1.0000x reference)
//
#include <hip/hip_runtime.h>
#include <hip/hip_bf16.h>

#define Nn 20000
#define Dd 256
#define Ff 256
#define Kc 32
#define NP2 20032           // xpre_t padded cols (313*64), zeros past 20000
#define NSPLIT 13
#define NMT 79              // ceil(20000/256) m-tiles

typedef __attribute__((ext_vector_type(8))) short short8;
typedef __attribute__((ext_vector_type(4))) short short4_t;
typedef __attribute__((ext_vector_type(4))) float float4_t;

static __device__ __forceinline__ short f2bf(float x) {
    union { float f; unsigned u; } v; v.f = x;
    unsigned r = v.u + 0x7FFFu + ((v.u >> 16) & 1u);   // round-to-nearest-even
    return (short)(r >> 16);
}
static __device__ __forceinline__ short4_t cvt4(float4_t v) {
    short4_t r; r[0] = f2bf(v[0]); r[1] = f2bf(v[1]); r[2] = f2bf(v[2]); r[3] = f2bf(v[3]);
    return r;
}
static __device__ __forceinline__ unsigned cvtpk(float a, float b) {
    unsigned r;
    asm("v_cvt_pk_bf16_f32 %0, %1, %2" : "=v"(r) : "v"(a), "v"(b));
    return r;   // lo = bf16(a), hi = bf16(b)  (RNE)
}

// ---------------- K1: node = h @ W1  [N,32] fp32 ----------------
__global__ __launch_bounds__(256) void k_node(const float* __restrict__ h,
                                              const float* __restrict__ W1,
                                              float* __restrict__ node) {
    int t = blockIdx.x * 256 + threadIdx.x;
    int n = t >> 5, k = t & 31;
    if (n >= Nn) return;
    const float4_t* hr = (const float4_t*)(h + (size_t)n * Dd);
    float s = 0.f;
    #pragma unroll 8
    for (int d4 = 0; d4 < 64; ++d4) {
        float4_t hv = hr[d4];
        #pragma unroll
        for (int j = 0; j < 4; ++j) s += hv[j] * W1[(d4 * 4 + j) * Kc + k];
    }
    node[n * Kc + k] = s;
}

// ---------------- K1b: out = node @ b (bias pre-pass; k_aggr atomicAdds) ---
__global__ __launch_bounds__(256) void k_bias(const float* __restrict__ node,
                                              const float* __restrict__ bb,
                                              float* __restrict__ out) {
    int n = blockIdx.x, f = threadIdx.x;
    const float* nr = node + (size_t)n * Kc;
    float s = 0.f;
    #pragma unroll
    for (int k = 0; k < Kc; ++k) s += nr[k] * bb[k * Ff + f];
    out[(size_t)n * Ff + f] = s;
}

// ------- K2: pack W2 (fp32 [32][256][256]) -> bf16 B-fragment order -------
__global__ __launch_bounds__(256) void k_packW2(const float* __restrict__ W2,
                                                short* __restrict__ P) {
    int t = blockIdx.x * 256 + threadIdx.x;
    int lane = t & 63;
    int cf = (t >> 6) & 15;
    int dc = (t >> 10) & 7;
    int kk = t >> 13;
    int col = cf * 16 + (lane & 15);
    int d0  = dc * 32 + (lane >> 4) * 8;
    const float* src = W2 + ((size_t)(kk * Dd + d0)) * Ff + col;
    short8 v;
    #pragma unroll
    for (int j = 0; j < 8; ++j) v[j] = f2bf(src[(size_t)j * Ff]);
    *(short8*)(P + (size_t)t * 8) = v;
}

// ---------------- K3: x_pre, stored transposed bf16 [256][NP2] ----------------
__global__ __launch_bounds__(256, 2) void k_xpre(const float* __restrict__ h,
                                                 const float* __restrict__ node,
                                                 const short* __restrict__ P,
                                                 short* __restrict__ xpre_t) {
    __shared__ short hlds[64 * 264];
    __shared__ float ntl[32 * 64];
    int t = threadIdx.x;
    int n0 = blockIdx.x * 64;

    #pragma unroll
    for (int i = 0; i < 16; ++i) {
        int c = t + i * 256;
        int row = c >> 6, cc = c & 63;
        int n = n0 + row; if (n > Nn - 1) n = Nn - 1;
        float4_t v = *(const float4_t*)(h + (size_t)n * Dd + cc * 4);
        *(short4_t*)&hlds[row * 264 + cc * 4] = cvt4(v);
    }
    #pragma unroll
    for (int i = 0; i < 8; ++i) {
        int idx = t + i * 256;
        int nl = idx >> 5, k = idx & 31;
        int n = n0 + nl; if (n > Nn - 1) n = Nn - 1;
        ntl[k * 64 + nl] = node[(size_t)n * Kc + k];
    }
    __syncthreads();

    int lane = t & 63, w = t >> 6;
    int arow = lane & 15;
    int asel = (lane >> 4) * 8;
    float4_t acc[4][4];
    #pragma unroll
    for (int a = 0; a < 4; ++a)
        #pragma unroll
        for (int b2 = 0; b2 < 4; ++b2) acc[a][b2] = (float4_t){0.f, 0.f, 0.f, 0.f};

    for (int kk = 0; kk < 32; ++kk) {
        float4_t T[4][4];
        #pragma unroll
        for (int a = 0; a < 4; ++a)
            #pragma unroll
            for (int b2 = 0; b2 < 4; ++b2) T[a][b2] = (float4_t){0.f, 0.f, 0.f, 0.f};
        #pragma unroll
        for (int dc = 0; dc < 8; ++dc) {
            short8 af[4], bfr[4];
            #pragma unroll
            for (int rf = 0; rf < 4; ++rf)
                af[rf] = *(const short8*)&hlds[(rf * 16 + arow) * 264 + dc * 32 + asel];
            #pragma unroll
            for (int cf = 0; cf < 4; ++cf)
                bfr[cf] = *(const short8*)(P + ((size_t)(((kk * 8 + dc) * 16 + w * 4 + cf) * 64 + lane)) * 8);
            #pragma unroll
            for (int rf = 0; rf < 4; ++rf)
                #pragma unroll
                for (int cf = 0; cf < 4; ++cf)
                    T[rf][cf] = __builtin_amdgcn_mfma_f32_16x16x32_bf16(af[rf], bfr[cf], T[rf][cf], 0, 0, 0);
        }
        #pragma unroll
        for (int rf = 0; rf < 4; ++rf) {
            float4_t sc = *(const float4_t*)&ntl[kk * 64 + rf * 16 + (lane >> 4) * 4];
            #pragma unroll
            for (int cf = 0; cf < 4; ++cf)
                #pragma unroll
                for (int r = 0; r < 4; ++r)
                    acc[rf][cf][r] += sc[r] * T[rf][cf][r];
        }
    }

    #pragma unroll
    for (int rf = 0; rf < 4; ++rf) {
        int nl = rf * 16 + (lane >> 4) * 4;
        #pragma unroll
        for (int cf = 0; cf < 4; ++cf) {
            int f = w * 64 + cf * 16 + (lane & 15);
            #pragma unroll
            for (int r = 0; r < 4; ++r) {
                int n = n0 + nl + r;
                if (n < Nn)       xpre_t[(size_t)f * NP2 + n] = f2bf(acc[rf][cf][r]);
                else if (n < NP2) xpre_t[(size_t)f * NP2 + n] = 0;
            }
        }
    }
}

// ---------------- K4: out += adj @ x_pre (atomic, split-K x13) ----------------
// BM=256 (79 m-tiles), BN=256, BK=64, 1024 threads (16 waves = 4M x 4N).
// B re-read volume = 79 x 10 MB = 0.81 GB (vs 3.1 GB at BM=64) — the lever.
// A: reg-staged fp32->bf16 into 64KB XOR-swizzled LDS dbuf, 1-step prefetch.
// B: register dbuf, 1-step prefetch (static x2 unroll). 1 raw barrier/step.
__global__ __launch_bounds__(1024, 1) void k_aggr(const float* __restrict__ adj,
                                                  const short* __restrict__ xpre_t,
                                                  float* __restrict__ out) {
    __shared__ short albuf[2][16384];       // [256 rows][64 k] bf16, XOR-swizzled

    const int t = threadIdx.x;
    const int lane = t & 63, w = t >> 6;
    const int wm = w >> 2, wn = w & 3;      // 4M x 4N wave grid
    const int bid = blockIdx.x;
    const int mt = bid % NMT, split = bid / NMT;
    const int m0 = mt * 256;
    const int s_lo = (split == 0) ? 0 : 25 + (split - 1) * 24;
    const int ns   = (split == 0) ? 25 : 24;

    // A staging geometry: thread t loads rows (t>>4)+64i, k-chunk (t&15)*4
    const int kg4 = (t & 15) * 4;
    long rowbase[4];
    #pragma unroll
    for (int i = 0; i < 4; ++i) {
        int r = m0 + (t >> 4) + 64 * i; if (r > Nn - 1) r = Nn - 1;
        rowbase[i] = (long)r * Nn;
    }
    // B fragment pointers: wave cols wn*64 + cf*16 + (lane&15)
    const short* bp[4];
    #pragma unroll
    for (int cf = 0; cf < 4; ++cf)
        bp[cf] = xpre_t + (long)(wn * 64 + cf * 16 + (lane & 15)) * NP2 + (lane >> 4) * 8;

    float4_t acc[4][4];
    #pragma unroll
    for (int rf = 0; rf < 4; ++rf)
        #pragma unroll
        for (int cf = 0; cf < 4; ++cf) acc[rf][cf] = (float4_t){0.f, 0.f, 0.f, 0.f};

    float4_t A0[4], A1[4];
    short8 BA[4][2], BB[4][2];

#define ISSUEA(Ad, s_) do { int ko = (s_) * 64 + kg4; if (ko > Nn - 4) ko = Nn - 4; \
        _Pragma("unroll") for (int i = 0; i < 4; ++i) \
            Ad[i] = *(const float4_t*)(adj + rowbase[i] + ko); } while (0)

#define ISSUEB(Bd, s_) do { int sc_ = (s_) > 312 ? 312 : (s_); long off = (long)sc_ * 64; \
        _Pragma("unroll") for (int cf = 0; cf < 4; ++cf) { \
            Bd[cf][0] = *(const short8*)(bp[cf] + off); \
            Bd[cf][1] = *(const short8*)(bp[cf] + off + 32); } } while (0)

#define WRA(As, p_) do { _Pragma("unroll") for (int i = 0; i < 4; ++i) { \
        int r = (t >> 4) + 64 * i; \
        int idx = (r * 64 + kg4) ^ ((r & 7) << 3); \
        union { short4_t s4; unsigned u[2]; } uu; \
        uu.u[0] = cvtpk(As[i][0], As[i][1]); uu.u[1] = cvtpk(As[i][2], As[i][3]); \
        *(short4_t*)&albuf[p_][idx] = uu.s4; } } while (0)

#define COMP(Bc, p_) do { _Pragma("unroll") for (int dc = 0; dc < 2; ++dc) \
        _Pragma("unroll") for (int rf = 0; rf < 4; ++rf) { \
            int r = wm * 64 + rf * 16 + (lane & 15); \
            int c = dc * 32 + (lane >> 4) * 8; \
            short8 af = *(const short8*)&albuf[p_][(r * 64 + c) ^ ((r & 7) << 3)]; \
            _Pragma("unroll") for (int cf = 0; cf < 4; ++cf) \
                acc[rf][cf] = __builtin_amdgcn_mfma_f32_16x16x32_bf16(af, Bc[cf][dc], acc[rf][cf], 0, 0, 0); } } while (0)

// One raw barrier per step. Ledger: WRA(s)->buf[p]; lgkm drains my writes;
// barrier: all waves wrote; COMP reads buf[p] (auto lgkm waits before MFMA
// drain the reads before this wave's next ds_write). w(s+1) targets buf[p^1];
// w(s+2) targets buf[p] again but sits after bar(s+1) while every wave's
// r(s) completed before it reached bar(s+1). Global prefetches (A/B of s+1)
// stay in flight across the barrier — compiler emits counted vmcnt waits.
#define STEP(Ac, An, Bc, Bn, p_, ls_) do { \
        ISSUEA(An, s_lo + (ls_) + 1); \
        ISSUEB(Bn, s_lo + (ls_) + 1); \
        WRA(Ac, p_); \
        asm volatile("s_waitcnt lgkmcnt(0)" ::: "memory"); \
        __builtin_amdgcn_s_barrier(); \
        COMP(Bc, p_); } while (0)

    // prologue
    ISSUEA(A0, s_lo);
    ISSUEB(BA, s_lo);

    #pragma unroll 1
    for (int p = 0; p < (ns >> 1); ++p) {
        const int ls = 2 * p;
        STEP(A0, A1, BA, BB, 0, ls);
        STEP(A1, A0, BB, BA, 1, ls + 1);
    }
    if (ns & 1) STEP(A0, A1, BA, BB, 0, ns - 1);

    // epilogue: atomic accumulate onto bias-initialized out
    #pragma unroll
    for (int rf = 0; rf < 4; ++rf) {
        #pragma unroll
        for (int cf = 0; cf < 4; ++cf) {
            const int fl = wn * 64 + cf * 16 + (lane & 15);
            #pragma unroll
            for (int q = 0; q < 4; ++q) {
                int n = m0 + wm * 64 + rf * 16 + (lane >> 4) * 4 + q;
                if (n < Nn) atomicAdd(out + (size_t)n * Ff + fl, acc[rf][cf][q]);
            }
        }
    }
#undef ISSUEA
#undef ISSUEB
#undef WRA
#undef COMP
#undef STEP
}

// ---------------- K5: out = relu(out) ----------------
__global__ __launch_bounds__(256) void k_final(float* __restrict__ out) {
    int i = blockIdx.x * 256 + threadIdx.x;     // 640000 threads, 2 float4 each
    float4_t* o = (float4_t*)out;
    #pragma unroll
    for (int j = 0; j < 2; ++j) {
        int idx = i + j * 640000;
        float4_t v = o[idx];
        #pragma unroll
        for (int q = 0; q < 4; ++q) v[q] = v[q] > 0.f ? v[q] : 0.f;
        o[idx] = v;
    }
}

extern "C" void kernel_launch(void* const* d_in, const int* in_sizes, int n_in,
                              void* d_out, int out_size, void* d_ws, size_t ws_size,
                              hipStream_t stream) {
    const float* h   = (const float*)d_in[0];
    const float* adj = (const float*)d_in[1];
    const float* W1  = (const float*)d_in[2];
    const float* W2  = (const float*)d_in[3];
    const float* b   = (const float*)d_in[4];
    float* out = (float*)d_out;

    char* ws = (char*)d_ws;
    float* node   = (float*)ws;                               // 2,560,000 B
    short* P      = (short*)(ws + 2560000);                   // 4,194,304 B
    short* xpre_t = (short*)(ws + 2560000 + 4194304);         // 10,256,384 B (256 x 20032)

    k_node  <<<2500, 256, 0, stream>>>(h, W1, node);
    k_bias  <<<Nn,   256, 0, stream>>>(node, b, out);
    k_packW2<<<1024, 256, 0, stream>>>(W2, P);
    k_xpre  <<<313,  256, 0, stream>>>(h, node, P, xpre_t);
    k_aggr  <<<NMT * NSPLIT, 1024, 0, stream>>>(adj, xpre_t, out);
    k_final <<<2500, 256, 0, stream>>>(out);
}

// Round 8
// 1615.898 us; speedup vs baseline: 1.7188x; 1.7188x over previous
//
#include <hip/hip_runtime.h>
#include <hip/hip_bf16.h>

#define Nn 20000
#define Dd 256
#define Ff 256
#define Kc 32
#define NP2 20032           // xpre_t padded cols (313*64), zeros past 20000
#define NSPLIT 13
#define NMT 79              // ceil(20000/256) m-tiles

typedef __attribute__((ext_vector_type(8))) short short8;
typedef __attribute__((ext_vector_type(4))) short short4_t;
typedef __attribute__((ext_vector_type(4))) float float4_t;

static __device__ __forceinline__ short f2bf(float x) {
    union { float f; unsigned u; } v; v.f = x;
    unsigned r = v.u + 0x7FFFu + ((v.u >> 16) & 1u);   // round-to-nearest-even
    return (short)(r >> 16);
}
static __device__ __forceinline__ short4_t cvt4(float4_t v) {
    short4_t r; r[0] = f2bf(v[0]); r[1] = f2bf(v[1]); r[2] = f2bf(v[2]); r[3] = f2bf(v[3]);
    return r;
}
static __device__ __forceinline__ unsigned cvtpk(float a, float b) {
    unsigned r;
    asm("v_cvt_pk_bf16_f32 %0, %1, %2" : "=v"(r) : "v"(a), "v"(b));
    return r;   // lo = bf16(a), hi = bf16(b)  (RNE)
}
static __device__ __forceinline__ void glds16(const float* g, float* l) {
    __builtin_amdgcn_global_load_lds(
        (const __attribute__((address_space(1))) unsigned int*)g,
        (__attribute__((address_space(3))) unsigned int*)l,
        16, 0, 0);
}

// ---------------- K1: node = h @ W1  [N,32] fp32 ----------------
__global__ __launch_bounds__(256) void k_node(const float* __restrict__ h,
                                              const float* __restrict__ W1,
                                              float* __restrict__ node) {
    int t = blockIdx.x * 256 + threadIdx.x;
    int n = t >> 5, k = t & 31;
    if (n >= Nn) return;
    const float4_t* hr = (const float4_t*)(h + (size_t)n * Dd);
    float s = 0.f;
    #pragma unroll 8
    for (int d4 = 0; d4 < 64; ++d4) {
        float4_t hv = hr[d4];
        #pragma unroll
        for (int j = 0; j < 4; ++j) s += hv[j] * W1[(d4 * 4 + j) * Kc + k];
    }
    node[n * Kc + k] = s;
}

// ---------------- K1b: out = node @ b (bias pre-pass; k_aggr atomicAdds) ---
__global__ __launch_bounds__(256) void k_bias(const float* __restrict__ node,
                                              const float* __restrict__ bb,
                                              float* __restrict__ out) {
    int n = blockIdx.x, f = threadIdx.x;
    const float* nr = node + (size_t)n * Kc;
    float s = 0.f;
    #pragma unroll
    for (int k = 0; k < Kc; ++k) s += nr[k] * bb[k * Ff + f];
    out[(size_t)n * Ff + f] = s;
}

// ------- K2: pack W2 (fp32 [32][256][256]) -> bf16 B-fragment order -------
__global__ __launch_bounds__(256) void k_packW2(const float* __restrict__ W2,
                                                short* __restrict__ P) {
    int t = blockIdx.x * 256 + threadIdx.x;
    int lane = t & 63;
    int cf = (t >> 6) & 15;
    int dc = (t >> 10) & 7;
    int kk = t >> 13;
    int col = cf * 16 + (lane & 15);
    int d0  = dc * 32 + (lane >> 4) * 8;
    const float* src = W2 + ((size_t)(kk * Dd + d0)) * Ff + col;
    short8 v;
    #pragma unroll
    for (int j = 0; j < 8; ++j) v[j] = f2bf(src[(size_t)j * Ff]);
    *(short8*)(P + (size_t)t * 8) = v;
}

// ---------------- K3: x_pre, stored transposed bf16 [256][NP2] ----------------
__global__ __launch_bounds__(256, 2) void k_xpre(const float* __restrict__ h,
                                                 const float* __restrict__ node,
                                                 const short* __restrict__ P,
                                                 short* __restrict__ xpre_t) {
    __shared__ short hlds[64 * 264];
    __shared__ float ntl[32 * 64];
    int t = threadIdx.x;
    int n0 = blockIdx.x * 64;

    #pragma unroll
    for (int i = 0; i < 16; ++i) {
        int c = t + i * 256;
        int row = c >> 6, cc = c & 63;
        int n = n0 + row; if (n > Nn - 1) n = Nn - 1;
        float4_t v = *(const float4_t*)(h + (size_t)n * Dd + cc * 4);
        *(short4_t*)&hlds[row * 264 + cc * 4] = cvt4(v);
    }
    #pragma unroll
    for (int i = 0; i < 8; ++i) {
        int idx = t + i * 256;
        int nl = idx >> 5, k = idx & 31;
        int n = n0 + nl; if (n > Nn - 1) n = Nn - 1;
        ntl[k * 64 + nl] = node[(size_t)n * Kc + k];
    }
    __syncthreads();

    int lane = t & 63, w = t >> 6;
    int arow = lane & 15;
    int asel = (lane >> 4) * 8;
    float4_t acc[4][4];
    #pragma unroll
    for (int a = 0; a < 4; ++a)
        #pragma unroll
        for (int b2 = 0; b2 < 4; ++b2) acc[a][b2] = (float4_t){0.f, 0.f, 0.f, 0.f};

    for (int kk = 0; kk < 32; ++kk) {
        float4_t T[4][4];
        #pragma unroll
        for (int a = 0; a < 4; ++a)
            #pragma unroll
            for (int b2 = 0; b2 < 4; ++b2) T[a][b2] = (float4_t){0.f, 0.f, 0.f, 0.f};
        #pragma unroll
        for (int dc = 0; dc < 8; ++dc) {
            short8 af[4], bfr[4];
            #pragma unroll
            for (int rf = 0; rf < 4; ++rf)
                af[rf] = *(const short8*)&hlds[(rf * 16 + arow) * 264 + dc * 32 + asel];
            #pragma unroll
            for (int cf = 0; cf < 4; ++cf)
                bfr[cf] = *(const short8*)(P + ((size_t)(((kk * 8 + dc) * 16 + w * 4 + cf) * 64 + lane)) * 8);
            #pragma unroll
            for (int rf = 0; rf < 4; ++rf)
                #pragma unroll
                for (int cf = 0; cf < 4; ++cf)
                    T[rf][cf] = __builtin_amdgcn_mfma_f32_16x16x32_bf16(af[rf], bfr[cf], T[rf][cf], 0, 0, 0);
        }
        #pragma unroll
        for (int rf = 0; rf < 4; ++rf) {
            float4_t sc = *(const float4_t*)&ntl[kk * 64 + rf * 16 + (lane >> 4) * 4];
            #pragma unroll
            for (int cf = 0; cf < 4; ++cf)
                #pragma unroll
                for (int r = 0; r < 4; ++r)
                    acc[rf][cf][r] += sc[r] * T[rf][cf][r];
        }
    }

    #pragma unroll
    for (int rf = 0; rf < 4; ++rf) {
        int nl = rf * 16 + (lane >> 4) * 4;
        #pragma unroll
        for (int cf = 0; cf < 4; ++cf) {
            int f = w * 64 + cf * 16 + (lane & 15);
            #pragma unroll
            for (int r = 0; r < 4; ++r) {
                int n = n0 + nl + r;
                if (n < Nn)       xpre_t[(size_t)f * NP2 + n] = f2bf(acc[rf][cf][r]);
                else if (n < NP2) xpre_t[(size_t)f * NP2 + n] = 0;
            }
        }
    }
}

// ---------------- K4: out += adj @ x_pre (atomic, split-K x13) ----------------
// BM=256, BN=256, BK=64, 512 threads (8 waves = 2M x 4N; 2 waves/SIMD ->
// 256-reg cap, acc 128 + B dbuf 64 fits, NO spill). A staged fp32 via
// global_load_lds into 2x64KB LDS dbuf (16B-slot XOR swizzle, pre-swizzled
// source); bf16 cvt at read. vmcnt(16) counted wait; 2 raw barriers/step.
__global__ __launch_bounds__(512, 2) void k_aggr(const float* __restrict__ adj,
                                                 const short* __restrict__ xpre_t,
                                                 float* __restrict__ out) {
    __shared__ float albuf[2][16384];       // [256 rows][64 k] fp32, swizzled

    const int t = threadIdx.x;
    const int lane = t & 63, w = t >> 6;
    const int wm = w >> 2, wn = w & 3;      // 2M x 4N wave grid
    const int bid = blockIdx.x;
    const int mt = bid % NMT, split = bid / NMT;
    const int m0 = mt * 256;
    const int s_lo = (split == 0) ? 0 : 25 + (split - 1) * 24;
    const int ns   = (split == 0) ? 25 : 24;

    // glds geometry: thread t -> float4 chunks c = t + 512i; row=c>>4, slot=c&15
    const int tr = t >> 4;
    const int colp = (((t & 15) ^ (tr & 15)) << 2);   // pre-swizzled source col
    const int wglds = w * 256;                        // uniform LDS float base
    int adjoff[8];
    #pragma unroll
    for (int i = 0; i < 8; ++i) {
        int r = m0 + tr + 32 * i; if (r > Nn - 1) r = Nn - 1;
        adjoff[i] = r * Nn;                           // < 4.0e8, fits int
    }
    // B fragment pointers: wave cols wn*64 + cf*16 + (lane&15)
    const short* bp[4];
    #pragma unroll
    for (int cf = 0; cf < 4; ++cf)
        bp[cf] = xpre_t + (long)(wn * 64 + cf * 16 + (lane & 15)) * NP2 + (lane >> 4) * 8;

    float4_t acc[8][4];
    #pragma unroll
    for (int rf = 0; rf < 8; ++rf)
        #pragma unroll
        for (int cf = 0; cf < 4; ++cf) acc[rf][cf] = (float4_t){0.f, 0.f, 0.f, 0.f};

    short8 BA[4][2], BB[4][2];

#define ISSUEGLDS(p_, s_) do { \
        int kc = (s_) * 64 + colp; if (kc > Nn - 4) kc = Nn - 4; \
        _Pragma("unroll") for (int i = 0; i < 8; ++i) \
            glds16(adj + adjoff[i] + kc, &albuf[p_][wglds + i * 2048]); } while (0)

#define ISSUEB(Bd, s_) do { int sc_ = (s_) > 312 ? 312 : (s_); \
        _Pragma("unroll") for (int cf = 0; cf < 4; ++cf) { \
            Bd[cf][0] = *(const short8*)(bp[cf] + (long)sc_ * 64); \
            Bd[cf][1] = *(const short8*)(bp[cf] + (long)sc_ * 64 + 32); } } while (0)

#define COMP(Bc, p_) do { _Pragma("unroll") for (int dc = 0; dc < 2; ++dc) \
        _Pragma("unroll") for (int rf = 0; rf < 8; ++rf) { \
            const int r = wm * 128 + rf * 16 + (lane & 15); \
            const int s0 = dc * 8 + (lane >> 4) * 2; \
            float4_t lo = *(const float4_t*)&albuf[p_][r * 64 + (((s0    ) ^ (r & 15)) << 2)]; \
            float4_t hi = *(const float4_t*)&albuf[p_][r * 64 + (((s0 + 1) ^ (r & 15)) << 2)]; \
            union { short8 s8; unsigned u[4]; } af; \
            af.u[0] = cvtpk(lo[0], lo[1]); af.u[1] = cvtpk(lo[2], lo[3]); \
            af.u[2] = cvtpk(hi[0], hi[1]); af.u[3] = cvtpk(hi[2], hi[3]); \
            _Pragma("unroll") for (int cf = 0; cf < 4; ++cf) \
                acc[rf][cf] = __builtin_amdgcn_mfma_f32_16x16x32_bf16(af.s8, Bc[cf][dc], acc[rf][cf], 0, 0, 0); } } while (0)

// Step s: issue B(s+1)+glds A(s+1)->buf[p^1]; vmcnt(16) keeps those 16 in
// flight, drains A(s)(in buf[p]) and B(s)(regs Bc); barrier; compute;
// barrier2 protects buf[p] from step s+1's glds. Ledger: glds(s+1) writes
// buf[p^1], whose readers (COMP(s-1)) all passed barrier2(s-1) already.
#define STEP(Bc, Bn, p_, ls_) do { \
        ISSUEB(Bn, s_lo + (ls_) + 1); \
        ISSUEGLDS(p_ ^ 1, s_lo + (ls_) + 1); \
        asm volatile("s_waitcnt vmcnt(16)" ::: "memory"); \
        __builtin_amdgcn_s_barrier(); \
        asm volatile("" ::: "memory"); \
        COMP(Bc, p_); \
        asm volatile("" ::: "memory"); \
        __builtin_amdgcn_s_barrier(); } while (0)

    // prologue: A(s_lo) -> buf0, B(s_lo) -> BA
    ISSUEGLDS(0, s_lo);
    ISSUEB(BA, s_lo);

    #pragma unroll 1
    for (int p = 0; p < (ns >> 1); ++p) {
        STEP(BA, BB, 0, 2 * p);
        STEP(BB, BA, 1, 2 * p + 1);
    }
    if (ns & 1) STEP(BA, BB, 0, ns - 1);
    asm volatile("s_waitcnt vmcnt(0)" ::: "memory");   // no glds outlives the WG

    // epilogue: atomic accumulate onto bias-initialized out
    #pragma unroll
    for (int rf = 0; rf < 8; ++rf) {
        #pragma unroll
        for (int cf = 0; cf < 4; ++cf) {
            const int fl = wn * 64 + cf * 16 + (lane & 15);
            #pragma unroll
            for (int q = 0; q < 4; ++q) {
                int n = m0 + wm * 128 + rf * 16 + (lane >> 4) * 4 + q;
                if (n < Nn) atomicAdd(out + (size_t)n * Ff + fl, acc[rf][cf][q]);
            }
        }
    }
#undef ISSUEGLDS
#undef ISSUEB
#undef COMP
#undef STEP
}

// ---------------- K5: out = relu(out) ----------------
__global__ __launch_bounds__(256) void k_final(float* __restrict__ out) {
    int i = blockIdx.x * 256 + threadIdx.x;     // 640000 threads, 2 float4 each
    float4_t* o = (float4_t*)out;
    #pragma unroll
    for (int j = 0; j < 2; ++j) {
        int idx = i + j * 640000;
        float4_t v = o[idx];
        #pragma unroll
        for (int q = 0; q < 4; ++q) v[q] = v[q] > 0.f ? v[q] : 0.f;
        o[idx] = v;
    }
}

extern "C" void kernel_launch(void* const* d_in, const int* in_sizes, int n_in,
                              void* d_out, int out_size, void* d_ws, size_t ws_size,
                              hipStream_t stream) {
    const float* h   = (const float*)d_in[0];
    const float* adj = (const float*)d_in[1];
    const float* W1  = (const float*)d_in[2];
    const float* W2  = (const float*)d_in[3];
    const float* b   = (const float*)d_in[4];
    float* out = (float*)d_out;

    char* ws = (char*)d_ws;
    float* node   = (float*)ws;                               // 2,560,000 B
    short* P      = (short*)(ws + 2560000);                   // 4,194,304 B
    short* xpre_t = (short*)(ws + 2560000 + 4194304);         // 10,256,384 B (256 x 20032)

    k_node  <<<2500, 256, 0, stream>>>(h, W1, node);
    k_bias  <<<Nn,   256, 0, stream>>>(node, b, out);
    k_packW2<<<1024, 256, 0, stream>>>(W2, P);
    k_xpre  <<<313,  256, 0, stream>>>(h, node, P, xpre_t);
    k_aggr  <<<NMT * NSPLIT, 512, 0, stream>>>(adj, xpre_t, out);
    k_final <<<2500, 256, 0, stream>>>(out);
}

// Round 9
// 1027.256 us; speedup vs baseline: 2.7037x; 1.5730x over previous
//
#include <hip/hip_runtime.h>
#include <hip/hip_bf16.h>

#define Nn 20000
#define Dd 256
#define Ff 256
#define Kc 32
#define NP2 20032           // xpre_t padded cols (313*64), zeros past 20000
#define NSPLIT 6
#define NMT 157             // ceil(20000/128) m-tiles, BM=128

typedef __attribute__((ext_vector_type(8))) short short8;
typedef __attribute__((ext_vector_type(4))) short short4_t;
typedef __attribute__((ext_vector_type(4))) float float4_t;

static __device__ __forceinline__ short f2bf(float x) {
    union { float f; unsigned u; } v; v.f = x;
    unsigned r = v.u + 0x7FFFu + ((v.u >> 16) & 1u);   // round-to-nearest-even
    return (short)(r >> 16);
}
static __device__ __forceinline__ short4_t cvt4(float4_t v) {
    short4_t r; r[0] = f2bf(v[0]); r[1] = f2bf(v[1]); r[2] = f2bf(v[2]); r[3] = f2bf(v[3]);
    return r;
}
static __device__ __forceinline__ unsigned cvtpk(float a, float b) {
    unsigned r;
    asm("v_cvt_pk_bf16_f32 %0, %1, %2" : "=v"(r) : "v"(a), "v"(b));
    return r;   // lo = bf16(a), hi = bf16(b)  (RNE)
}
static __device__ __forceinline__ void glds16(const float* g, float* l) {
    __builtin_amdgcn_global_load_lds(
        (const __attribute__((address_space(1))) unsigned int*)g,
        (__attribute__((address_space(3))) unsigned int*)l,
        16, 0, 0);
}

// ---------------- K1: node = h @ W1  [N,32] fp32 ----------------
__global__ __launch_bounds__(256) void k_node(const float* __restrict__ h,
                                              const float* __restrict__ W1,
                                              float* __restrict__ node) {
    int t = blockIdx.x * 256 + threadIdx.x;
    int n = t >> 5, k = t & 31;
    if (n >= Nn) return;
    const float4_t* hr = (const float4_t*)(h + (size_t)n * Dd);
    float s = 0.f;
    #pragma unroll 8
    for (int d4 = 0; d4 < 64; ++d4) {
        float4_t hv = hr[d4];
        #pragma unroll
        for (int j = 0; j < 4; ++j) s += hv[j] * W1[(d4 * 4 + j) * Kc + k];
    }
    node[n * Kc + k] = s;
}

// ---------------- K1b: out = node @ b (bias pre-pass; k_aggr atomicAdds) ---
__global__ __launch_bounds__(256) void k_bias(const float* __restrict__ node,
                                              const float* __restrict__ bb,
                                              float* __restrict__ out) {
    int n = blockIdx.x, f = threadIdx.x;
    const float* nr = node + (size_t)n * Kc;
    float s = 0.f;
    #pragma unroll
    for (int k = 0; k < Kc; ++k) s += nr[k] * bb[k * Ff + f];
    out[(size_t)n * Ff + f] = s;
}

// ------- K2: pack W2 (fp32 [32][256][256]) -> bf16 B-fragment order -------
__global__ __launch_bounds__(256) void k_packW2(const float* __restrict__ W2,
                                                short* __restrict__ P) {
    int t = blockIdx.x * 256 + threadIdx.x;
    int lane = t & 63;
    int cf = (t >> 6) & 15;
    int dc = (t >> 10) & 7;
    int kk = t >> 13;
    int col = cf * 16 + (lane & 15);
    int d0  = dc * 32 + (lane >> 4) * 8;
    const float* src = W2 + ((size_t)(kk * Dd + d0)) * Ff + col;
    short8 v;
    #pragma unroll
    for (int j = 0; j < 8; ++j) v[j] = f2bf(src[(size_t)j * Ff]);
    *(short8*)(P + (size_t)t * 8) = v;
}

// ---------------- K3: x_pre, stored transposed bf16 [256][NP2] ----------------
__global__ __launch_bounds__(256, 2) void k_xpre(const float* __restrict__ h,
                                                 const float* __restrict__ node,
                                                 const short* __restrict__ P,
                                                 short* __restrict__ xpre_t) {
    __shared__ short hlds[64 * 264];
    __shared__ float ntl[32 * 64];
    int t = threadIdx.x;
    int n0 = blockIdx.x * 64;

    #pragma unroll
    for (int i = 0; i < 16; ++i) {
        int c = t + i * 256;
        int row = c >> 6, cc = c & 63;
        int n = n0 + row; if (n > Nn - 1) n = Nn - 1;
        float4_t v = *(const float4_t*)(h + (size_t)n * Dd + cc * 4);
        *(short4_t*)&hlds[row * 264 + cc * 4] = cvt4(v);
    }
    #pragma unroll
    for (int i = 0; i < 8; ++i) {
        int idx = t + i * 256;
        int nl = idx >> 5, k = idx & 31;
        int n = n0 + nl; if (n > Nn - 1) n = Nn - 1;
        ntl[k * 64 + nl] = node[(size_t)n * Kc + k];
    }
    __syncthreads();

    int lane = t & 63, w = t >> 6;
    int arow = lane & 15;
    int asel = (lane >> 4) * 8;
    float4_t acc[4][4];
    #pragma unroll
    for (int a = 0; a < 4; ++a)
        #pragma unroll
        for (int b2 = 0; b2 < 4; ++b2) acc[a][b2] = (float4_t){0.f, 0.f, 0.f, 0.f};

    for (int kk = 0; kk < 32; ++kk) {
        float4_t T[4][4];
        #pragma unroll
        for (int a = 0; a < 4; ++a)
            #pragma unroll
            for (int b2 = 0; b2 < 4; ++b2) T[a][b2] = (float4_t){0.f, 0.f, 0.f, 0.f};
        #pragma unroll
        for (int dc = 0; dc < 8; ++dc) {
            short8 af[4], bfr[4];
            #pragma unroll
            for (int rf = 0; rf < 4; ++rf)
                af[rf] = *(const short8*)&hlds[(rf * 16 + arow) * 264 + dc * 32 + asel];
            #pragma unroll
            for (int cf = 0; cf < 4; ++cf)
                bfr[cf] = *(const short8*)(P + ((size_t)(((kk * 8 + dc) * 16 + w * 4 + cf) * 64 + lane)) * 8);
            #pragma unroll
            for (int rf = 0; rf < 4; ++rf)
                #pragma unroll
                for (int cf = 0; cf < 4; ++cf)
                    T[rf][cf] = __builtin_amdgcn_mfma_f32_16x16x32_bf16(af[rf], bfr[cf], T[rf][cf], 0, 0, 0);
        }
        #pragma unroll
        for (int rf = 0; rf < 4; ++rf) {
            float4_t sc = *(const float4_t*)&ntl[kk * 64 + rf * 16 + (lane >> 4) * 4];
            #pragma unroll
            for (int cf = 0; cf < 4; ++cf)
                #pragma unroll
                for (int r = 0; r < 4; ++r)
                    acc[rf][cf][r] += sc[r] * T[rf][cf][r];
        }
    }

    #pragma unroll
    for (int rf = 0; rf < 4; ++rf) {
        int nl = rf * 16 + (lane >> 4) * 4;
        #pragma unroll
        for (int cf = 0; cf < 4; ++cf) {
            int f = w * 64 + cf * 16 + (lane & 15);
            #pragma unroll
            for (int r = 0; r < 4; ++r) {
                int n = n0 + nl + r;
                if (n < Nn)       xpre_t[(size_t)f * NP2 + n] = f2bf(acc[rf][cf][r]);
                else if (n < NP2) xpre_t[(size_t)f * NP2 + n] = 0;
            }
        }
    }
}

// ---------------- K4: out += adj @ x_pre (atomic, split-K x6) ----------------
// R6's proven pipeline (5.9 TB/s) scaled to BM=128: 3x32KB LDS ring, glds
// fp32 2 steps ahead, B reg-dbuf 1 step ahead, ONE raw barrier/step,
// vmcnt(12) counted (drains A(s)+B(s), keeps A(s+1)+B(s+1) in flight).
// 512 thr = 8 waves (2M x 4N, wave-tile 64x64). Grid 942 = 157 mt x 6 splits.
__global__ __launch_bounds__(512, 2) void k_aggr(const float* __restrict__ adj,
                                                 const short* __restrict__ xpre_t,
                                                 float* __restrict__ out) {
    __shared__ float lds0[8192], lds1[8192], lds2[8192];   // 3 x 32 KB

    const int t = threadIdx.x;
    const int lane = t & 63, w = t >> 6;
    const int wm = w >> 2, wn = w & 3;      // 2M x 4N wave grid
    const int bid = blockIdx.x;
    const int mt = bid % NMT, split = bid / NMT;
    const int m0 = mt * 128;
    const int s_lo = (split == 0) ? 0 : 53 + 52 * (split - 1);
    const int ns   = (split == 0) ? 53 : 52;

    // glds geometry: chunk c = t + 512i (i<4); row=c>>4 (16 slots/row), slot=t&15
    const int tr = t >> 4;                            // 0..31
    const int colp = (((t & 15) ^ (tr & 15)) << 2);   // pre-swizzled source col
    const int wglds = w * 256;                        // wave-uniform LDS float base
    int adjoff[4];
    #pragma unroll
    for (int i = 0; i < 4; ++i) {
        int r = m0 + tr + 32 * i; if (r > Nn - 1) r = Nn - 1;
        adjoff[i] = r * Nn;                           // < 4.0e8, fits int
    }
    // B fragment pointers: wave cols wn*64 + cf*16 + (lane&15)
    const short* bp[4];
    #pragma unroll
    for (int cf = 0; cf < 4; ++cf)
        bp[cf] = xpre_t + (long)(wn * 64 + cf * 16 + (lane & 15)) * NP2 + (lane >> 4) * 8;

    float4_t acc[4][4];
    #pragma unroll
    for (int rf = 0; rf < 4; ++rf)
        #pragma unroll
        for (int cf = 0; cf < 4; ++cf) acc[rf][cf] = (float4_t){0.f, 0.f, 0.f, 0.f};

    short8 BA[4][2], BB[4][2];
    float* pR = lds0; float* pM = lds1; float* pW = lds2;
    int s = 0;

#define ISSUEGLDS(pp_, s_) do { \
        int kc = (s_) * 64 + colp; if (kc > Nn - 4) kc = Nn - 4; \
        _Pragma("unroll") for (int i = 0; i < 4; ++i) \
            glds16(adj + adjoff[i] + kc, pp_ + wglds + i * 2048); } while (0)

#define ISSUEB(Bd, s_) do { int sc_ = (s_) > 312 ? 312 : (s_); \
        _Pragma("unroll") for (int cf = 0; cf < 4; ++cf) { \
            Bd[cf][0] = *(const short8*)(bp[cf] + (long)sc_ * 64); \
            Bd[cf][1] = *(const short8*)(bp[cf] + (long)sc_ * 64 + 32); } } while (0)

#define COMP(Bc) do { _Pragma("unroll") for (int dc = 0; dc < 2; ++dc) \
        _Pragma("unroll") for (int rf = 0; rf < 4; ++rf) { \
            const int r = wm * 64 + rf * 16 + (lane & 15); \
            const int s0 = dc * 8 + (lane >> 4) * 2; \
            float4_t lo = *(const float4_t*)&pR[r * 64 + (((s0    ) ^ (r & 15)) << 2)]; \
            float4_t hi = *(const float4_t*)&pR[r * 64 + (((s0 + 1) ^ (r & 15)) << 2)]; \
            union { short8 s8; unsigned u[4]; } af; \
            af.u[0] = cvtpk(lo[0], lo[1]); af.u[1] = cvtpk(lo[2], lo[3]); \
            af.u[2] = cvtpk(hi[0], hi[1]); af.u[3] = cvtpk(hi[2], hi[3]); \
            _Pragma("unroll") for (int cf = 0; cf < 4; ++cf) \
                acc[rf][cf] = __builtin_amdgcn_mfma_f32_16x16x32_bf16(af.s8, Bc[cf][dc], acc[rf][cf], 0, 0, 0); } } while (0)

// FIFO at vmcnt: [A(s)x4 (oldest), B(s)x8, A(s+1)x4, B(s+1)x8] -> vmcnt(12)
// drains A(s)+B(s) exactly. glds(s+2) issued AFTER COMP (ring slot pW was
// last read at COMP(s-1), all waves past barrier(s) -> safe; R6-proven).
#define STEP(Bc, Bn) do { \
        ISSUEB(Bn, s_lo + s + 1); \
        asm volatile("s_waitcnt vmcnt(12) lgkmcnt(0)" ::: "memory"); \
        __builtin_amdgcn_s_barrier(); \
        __builtin_amdgcn_sched_barrier(0); \
        COMP(Bc); \
        ISSUEGLDS(pW, s_lo + s + 2); \
        { float* tp_ = pR; pR = pM; pM = pW; pW = tp_; } \
        ++s; } while (0)

    // prologue: A(s_lo)->pR, B(s_lo)->BA, A(s_lo+1)->pM
    ISSUEGLDS(pR, s_lo);
    asm volatile("" ::: "memory");
    ISSUEB(BA, s_lo);
    asm volatile("" ::: "memory");
    ISSUEGLDS(pM, s_lo + 1);

    #pragma unroll 1
    for (int p = 0; p < (ns >> 1); ++p) {
        STEP(BA, BB);
        STEP(BB, BA);
    }
    if (ns & 1) STEP(BA, BB);
    asm volatile("s_waitcnt vmcnt(0)" ::: "memory");   // drain glds before teardown

    // epilogue: atomic accumulate onto bias-initialized out
    #pragma unroll
    for (int rf = 0; rf < 4; ++rf) {
        #pragma unroll
        for (int cf = 0; cf < 4; ++cf) {
            const int fl = wn * 64 + cf * 16 + (lane & 15);
            #pragma unroll
            for (int q = 0; q < 4; ++q) {
                int n = m0 + wm * 64 + rf * 16 + (lane >> 4) * 4 + q;
                if (n < Nn) atomicAdd(out + (size_t)n * Ff + fl, acc[rf][cf][q]);
            }
        }
    }
#undef ISSUEGLDS
#undef ISSUEB
#undef COMP
#undef STEP
}

// ---------------- K5: out = relu(out) ----------------
__global__ __launch_bounds__(256) void k_final(float* __restrict__ out) {
    int i = blockIdx.x * 256 + threadIdx.x;     // 640000 threads, 2 float4 each
    float4_t* o = (float4_t*)out;
    #pragma unroll
    for (int j = 0; j < 2; ++j) {
        int idx = i + j * 640000;
        float4_t v = o[idx];
        #pragma unroll
        for (int q = 0; q < 4; ++q) v[q] = v[q] > 0.f ? v[q] : 0.f;
        o[idx] = v;
    }
}

extern "C" void kernel_launch(void* const* d_in, const int* in_sizes, int n_in,
                              void* d_out, int out_size, void* d_ws, size_t ws_size,
                              hipStream_t stream) {
    const float* h   = (const float*)d_in[0];
    const float* adj = (const float*)d_in[1];
    const float* W1  = (const float*)d_in[2];
    const float* W2  = (const float*)d_in[3];
    const float* b   = (const float*)d_in[4];
    float* out = (float*)d_out;

    char* ws = (char*)d_ws;
    float* node   = (float*)ws;                               // 2,560,000 B
    short* P      = (short*)(ws + 2560000);                   // 4,194,304 B
    short* xpre_t = (short*)(ws + 2560000 + 4194304);         // 10,256,384 B (256 x 20032)

    k_node  <<<2500, 256, 0, stream>>>(h, W1, node);
    k_bias  <<<Nn,   256, 0, stream>>>(node, b, out);
    k_packW2<<<1024, 256, 0, stream>>>(W2, P);
    k_xpre  <<<313,  256, 0, stream>>>(h, node, P, xpre_t);
    k_aggr  <<<NMT * NSPLIT, 512, 0, stream>>>(adj, xpre_t, out);
    k_final <<<2500, 256, 0, stream>>>(out);
}

// Round 10
// 910.574 us; speedup vs baseline: 3.0501x; 1.1281x over previous
//
#include <hip/hip_runtime.h>
#include <hip/hip_bf16.h>

#define Nn 20000
#define Dd 256
#define Ff 256
#define Kc 32
#define NKB 628             // PB kb slots (626 used + 2 prefetch pad)

typedef __attribute__((ext_vector_type(8))) short short8;
typedef __attribute__((ext_vector_type(4))) short short4_t;
typedef __attribute__((ext_vector_type(4))) float float4_t;

static __device__ __forceinline__ short f2bf(float x) {
    union { float f; unsigned u; } v; v.f = x;
    unsigned r = v.u + 0x7FFFu + ((v.u >> 16) & 1u);   // round-to-nearest-even
    return (short)(r >> 16);
}
static __device__ __forceinline__ short4_t cvt4(float4_t v) {
    short4_t r; r[0] = f2bf(v[0]); r[1] = f2bf(v[1]); r[2] = f2bf(v[2]); r[3] = f2bf(v[3]);
    return r;
}
static __device__ __forceinline__ unsigned cvtpk(float a, float b) {
    unsigned r;
    asm("v_cvt_pk_bf16_f32 %0, %1, %2" : "=v"(r) : "v"(a), "v"(b));
    return r;   // lo = bf16(a), hi = bf16(b)  (RNE)
}
static __device__ __forceinline__ void glds16(const float* g, float* l) {
    __builtin_amdgcn_global_load_lds(
        (const __attribute__((address_space(1))) unsigned int*)g,
        (__attribute__((address_space(3))) unsigned int*)l,
        16, 0, 0);
}

// ---------------- K1: node = h @ W1  [N,32] fp32 ----------------
__global__ __launch_bounds__(256) void k_node(const float* __restrict__ h,
                                              const float* __restrict__ W1,
                                              float* __restrict__ node) {
    int t = blockIdx.x * 256 + threadIdx.x;
    int n = t >> 5, k = t & 31;
    if (n >= Nn) return;
    const float4_t* hr = (const float4_t*)(h + (size_t)n * Dd);
    float s = 0.f;
    #pragma unroll 8
    for (int d4 = 0; d4 < 64; ++d4) {
        float4_t hv = hr[d4];
        #pragma unroll
        for (int j = 0; j < 4; ++j) s += hv[j] * W1[(d4 * 4 + j) * Kc + k];
    }
    node[n * Kc + k] = s;
}

// ---------------- K1b: out = node @ b (bias pre-pass; k_aggr atomicAdds) ---
__global__ __launch_bounds__(256) void k_bias(const float* __restrict__ node,
                                              const float* __restrict__ bb,
                                              float* __restrict__ out) {
    int n = blockIdx.x, f = threadIdx.x;
    const float* nr = node + (size_t)n * Kc;
    float s = 0.f;
    #pragma unroll
    for (int k = 0; k < Kc; ++k) s += nr[k] * bb[k * Ff + f];
    out[(size_t)n * Ff + f] = s;
}

// ------- K2: pack W2 (fp32 [32][256][256]) -> bf16 B-fragment order -------
__global__ __launch_bounds__(256) void k_packW2(const float* __restrict__ W2,
                                                short* __restrict__ P) {
    int t = blockIdx.x * 256 + threadIdx.x;
    int lane = t & 63;
    int cf = (t >> 6) & 15;
    int dc = (t >> 10) & 7;
    int kk = t >> 13;
    int col = cf * 16 + (lane & 15);
    int d0  = dc * 32 + (lane >> 4) * 8;
    const float* src = W2 + ((size_t)(kk * Dd + d0)) * Ff + col;
    short8 v;
    #pragma unroll
    for (int j = 0; j < 8; ++j) v[j] = f2bf(src[(size_t)j * Ff]);
    *(short8*)(P + (size_t)t * 8) = v;
}

// ------ K3: x_pre -> PB, bf16 in MFMA-B-fragment order ------
// PB[((kb*16 + cf16)*64 + lane)*8 + j] = x_pre[k][f],
//   k = kb*32 + (lane>>4)*8 + j, f = cf16*16 + (lane&15); zeros for k>=Nn.
// Coalesced 16B packed stores (replaces 2B scatter at 40KB stride).
__global__ __launch_bounds__(256, 2) void k_xpre(const float* __restrict__ h,
                                                 const float* __restrict__ node,
                                                 const short* __restrict__ P,
                                                 short* __restrict__ PB) {
    __shared__ short hlds[64 * 264];        // bf16 h tile
    __shared__ float ntl[32 * 64];          // node transposed
    __shared__ short tlds[256 * 72];        // [f][n_loc] bf16 transpose tile
    int t = threadIdx.x;
    int n0 = blockIdx.x * 64;

    #pragma unroll
    for (int i = 0; i < 16; ++i) {
        int c = t + i * 256;
        int row = c >> 6, cc = c & 63;
        int n = n0 + row; if (n > Nn - 1) n = Nn - 1;
        float4_t v = *(const float4_t*)(h + (size_t)n * Dd + cc * 4);
        *(short4_t*)&hlds[row * 264 + cc * 4] = cvt4(v);
    }
    #pragma unroll
    for (int i = 0; i < 8; ++i) {
        int idx = t + i * 256;
        int nl = idx >> 5, k = idx & 31;
        int n = n0 + nl; if (n > Nn - 1) n = Nn - 1;
        ntl[k * 64 + nl] = node[(size_t)n * Kc + k];
    }
    __syncthreads();

    int lane = t & 63, w = t >> 6;
    int arow = lane & 15;
    int asel = (lane >> 4) * 8;
    float4_t acc[4][4];
    #pragma unroll
    for (int a = 0; a < 4; ++a)
        #pragma unroll
        for (int b2 = 0; b2 < 4; ++b2) acc[a][b2] = (float4_t){0.f, 0.f, 0.f, 0.f};

    for (int kk = 0; kk < 32; ++kk) {
        float4_t T[4][4];
        #pragma unroll
        for (int a = 0; a < 4; ++a)
            #pragma unroll
            for (int b2 = 0; b2 < 4; ++b2) T[a][b2] = (float4_t){0.f, 0.f, 0.f, 0.f};
        #pragma unroll
        for (int dc = 0; dc < 8; ++dc) {
            short8 af[4], bfr[4];
            #pragma unroll
            for (int rf = 0; rf < 4; ++rf)
                af[rf] = *(const short8*)&hlds[(rf * 16 + arow) * 264 + dc * 32 + asel];
            #pragma unroll
            for (int cf = 0; cf < 4; ++cf)
                bfr[cf] = *(const short8*)(P + ((size_t)(((kk * 8 + dc) * 16 + w * 4 + cf) * 64 + lane)) * 8);
            #pragma unroll
            for (int rf = 0; rf < 4; ++rf)
                #pragma unroll
                for (int cf = 0; cf < 4; ++cf)
                    T[rf][cf] = __builtin_amdgcn_mfma_f32_16x16x32_bf16(af[rf], bfr[cf], T[rf][cf], 0, 0, 0);
        }
        #pragma unroll
        for (int rf = 0; rf < 4; ++rf) {
            float4_t sc = *(const float4_t*)&ntl[kk * 64 + rf * 16 + (lane >> 4) * 4];
            #pragma unroll
            for (int cf = 0; cf < 4; ++cf)
                #pragma unroll
                for (int r = 0; r < 4; ++r)
                    acc[rf][cf][r] += sc[r] * T[rf][cf][r];
        }
    }

    // stage to transpose tile [f][n_loc] (zeros for n >= Nn)
    #pragma unroll
    for (int rf = 0; rf < 4; ++rf) {
        int nl = rf * 16 + (lane >> 4) * 4;
        #pragma unroll
        for (int cf = 0; cf < 4; ++cf) {
            int f = w * 64 + cf * 16 + (lane & 15);
            #pragma unroll
            for (int r = 0; r < 4; ++r) {
                int n = n0 + nl + r;
                tlds[f * 72 + nl + r] = (n < Nn) ? f2bf(acc[rf][cf][r]) : (short)0;
            }
        }
    }
    __syncthreads();

    // packed coalesced write: 8 fragment-lanes per thread
    const int kbase = blockIdx.x * 2;
    #pragma unroll
    for (int i = 0; i < 8; ++i) {
        int q = t + i * 256;                // 0..2047
        int kb_loc = q >> 10, rem = q & 1023;
        int cf16 = rem >> 6, lid = rem & 63;
        int f = cf16 * 16 + (lid & 15);
        int noff = kb_loc * 32 + (lid >> 4) * 8;
        short8 v = *(const short8*)&tlds[f * 72 + noff];
        *(short8*)(PB + ((size_t)((kbase + kb_loc) * 16 + cf16) * 64 + lid) * 8) = v;
    }
}

// ---------------- K4: out += adj @ x_pre (atomic, split-K x2) ----------------
// BM=64, BN=256, BK=64, 512 thr (8 waves, each: 64 rows x 32 cols, acc=32).
// A: glds fp32 2 steps ahead, 3x16KB LDS ring, 1 raw barrier/step.
// B: packed fragments — ONE contiguous 1KB load per (kb,cf) (the R9 fix:
// was a 64x16B gather over 640KB). vmcnt(6) = keep A(s+1)+B(s+1) in flight.
__global__ __launch_bounds__(512, 2) void k_aggr(const float* __restrict__ adj,
                                                 const short* __restrict__ PB,
                                                 float* __restrict__ out) {
    __shared__ float lds0[4096], lds1[4096], lds2[4096];   // 3 x 16 KB

    const int t = threadIdx.x;
    const int lane = t & 63, w = t >> 6;
    const int bid = blockIdx.x;
    const int split = bid >= 313;
    const int mt = split ? bid - 313 : bid;
    const int m0 = mt * 64;
    const int k0b = split ? 312 : 0;        // kb offset (k0 = 9984)
    const int s0k = split ? 156 : 0;        // step offset for adj k
    const int ns  = split ? 157 : 156;

    // glds geometry: chunk c = t + 512i (i<2); row = c>>4, slot = t&15
    const int tr = t >> 4;                  // 0..31
    const int colp = (((t & 15) ^ (tr & 15)) << 2);   // pre-swizzled src col
    const int wglds = w * 256;              // wave-uniform LDS float base
    int adjoff[2];
    #pragma unroll
    for (int i = 0; i < 2; ++i) {
        int r = m0 + tr + 32 * i; if (r > Nn - 1) r = Nn - 1;
        adjoff[i] = r * Nn;                 // < 4.0e8, fits int
    }

    float4_t acc[4][2];
    #pragma unroll
    for (int rf = 0; rf < 4; ++rf) {
        acc[rf][0] = (float4_t){0.f, 0.f, 0.f, 0.f};
        acc[rf][1] = (float4_t){0.f, 0.f, 0.f, 0.f};
    }
    short8 BA[2][2], BB[2][2];
    float* pR = lds0; float* pM = lds1; float* pW = lds2;
    int s = 0;

#define ISSUEGLDS(pp_, s_) do { \
        int kc = ((s0k + (s_)) * 64) + colp; if (kc > Nn - 4) kc = Nn - 4; \
        _Pragma("unroll") for (int i = 0; i < 2; ++i) \
            glds16(adj + adjoff[i] + kc, pp_ + wglds + i * 2048); } while (0)

#define ISSUEB(Bd, s_) do { size_t kb_ = (size_t)(k0b + 2 * (s_)); \
        _Pragma("unroll") for (int cf = 0; cf < 2; ++cf) \
        _Pragma("unroll") for (int dc = 0; dc < 2; ++dc) \
            Bd[cf][dc] = *(const short8*)(PB + (((kb_ + dc) * 16 + (w * 2 + cf)) * 64 + lane) * 8); } while (0)

#define COMP(Bc) do { _Pragma("unroll") for (int dc = 0; dc < 2; ++dc) \
        _Pragma("unroll") for (int rf = 0; rf < 4; ++rf) { \
            const int r = rf * 16 + (lane & 15); \
            const int sl = dc * 8 + (lane >> 4) * 2; \
            float4_t lo = *(const float4_t*)&pR[r * 64 + (((sl    ) ^ (r & 15)) << 2)]; \
            float4_t hi = *(const float4_t*)&pR[r * 64 + (((sl + 1) ^ (r & 15)) << 2)]; \
            union { short8 s8; unsigned u[4]; } af; \
            af.u[0] = cvtpk(lo[0], lo[1]); af.u[1] = cvtpk(lo[2], lo[3]); \
            af.u[2] = cvtpk(hi[0], hi[1]); af.u[3] = cvtpk(hi[2], hi[3]); \
            acc[rf][0] = __builtin_amdgcn_mfma_f32_16x16x32_bf16(af.s8, Bc[0][dc], acc[rf][0], 0, 0, 0); \
            acc[rf][1] = __builtin_amdgcn_mfma_f32_16x16x32_bf16(af.s8, Bc[1][dc], acc[rf][1], 0, 0, 0); } } while (0)

// FIFO: per step 6 ops (B 4 + glds 2). At vmcnt: [A(s)2, B(s)4 | A(s+1)2,
// B(s+1)4] -> vmcnt(6) drains A(s)+B(s) exactly. glds(s+2) after COMP
// (ring slot pW last read at COMP(s-1); all waves past barrier(s)).
#define STEP(Bc, Bn) do { \
        ISSUEB(Bn, s + 1); \
        asm volatile("s_waitcnt vmcnt(6) lgkmcnt(0)" ::: "memory"); \
        __builtin_amdgcn_s_barrier(); \
        __builtin_amdgcn_sched_barrier(0); \
        COMP(Bc); \
        ISSUEGLDS(pW, s + 2); \
        { float* tp_ = pR; pR = pM; pM = pW; pW = tp_; } \
        ++s; } while (0)

    // prologue: A(0)->pR, B(0)->BA, A(1)->pM
    ISSUEGLDS(pR, 0);
    asm volatile("" ::: "memory");
    ISSUEB(BA, 0);
    asm volatile("" ::: "memory");
    ISSUEGLDS(pM, 1);

    #pragma unroll 1
    for (int p = 0; p < (ns >> 1); ++p) {
        STEP(BA, BB);
        STEP(BB, BA);
    }
    if (ns & 1) STEP(BA, BB);
    asm volatile("s_waitcnt vmcnt(0)" ::: "memory");   // drain glds before exit

    // epilogue: atomic accumulate onto bias-initialized out
    #pragma unroll
    for (int rf = 0; rf < 4; ++rf) {
        #pragma unroll
        for (int cf = 0; cf < 2; ++cf) {
            const int fl = w * 32 + cf * 16 + (lane & 15);
            #pragma unroll
            for (int q = 0; q < 4; ++q) {
                int n = m0 + rf * 16 + (lane >> 4) * 4 + q;
                if (n < Nn) atomicAdd(out + (size_t)n * Ff + fl, acc[rf][cf][q]);
            }
        }
    }
#undef ISSUEGLDS
#undef ISSUEB
#undef COMP
#undef STEP
}

// ---------------- K5: out = relu(out) ----------------
__global__ __launch_bounds__(256) void k_final(float* __restrict__ out) {
    int i = blockIdx.x * 256 + threadIdx.x;     // 640000 threads, 2 float4 each
    float4_t* o = (float4_t*)out;
    #pragma unroll
    for (int j = 0; j < 2; ++j) {
        int idx = i + j * 640000;
        float4_t v = o[idx];
        #pragma unroll
        for (int q = 0; q < 4; ++q) v[q] = v[q] > 0.f ? v[q] : 0.f;
        o[idx] = v;
    }
}

extern "C" void kernel_launch(void* const* d_in, const int* in_sizes, int n_in,
                              void* d_out, int out_size, void* d_ws, size_t ws_size,
                              hipStream_t stream) {
    const float* h   = (const float*)d_in[0];
    const float* adj = (const float*)d_in[1];
    const float* W1  = (const float*)d_in[2];
    const float* W2  = (const float*)d_in[3];
    const float* b   = (const float*)d_in[4];
    float* out = (float*)d_out;

    char* ws = (char*)d_ws;
    float* node = (float*)ws;                                 // 2,560,000 B
    short* P    = (short*)(ws + 2560000);                     // 4,194,304 B
    short* PB   = (short*)(ws + 2560000 + 4194304);           // 10,289,152 B (628 kb x 8192 sh)

    k_node  <<<2500, 256, 0, stream>>>(h, W1, node);
    k_bias  <<<Nn,   256, 0, stream>>>(node, b, out);
    k_packW2<<<1024, 256, 0, stream>>>(W2, P);
    k_xpre  <<<313,  256, 0, stream>>>(h, node, P, PB);
    k_aggr  <<<626,  512, 0, stream>>>(adj, PB, out);
    k_final <<<2500, 256, 0, stream>>>(out);
}